// Round 2
// baseline (6048.177 us; speedup 1.0000x reference)
//
#include <hip/hip_runtime.h>
#include <math.h>

#define CDIV(a,b) (((a)+(b)-1)/(b))

constexpr int Bn = 256;
constexpr int Vn = 30000;
constexpr int Hn = 512;
constexpr int Kn = 200;
constexpr int En = 300;
constexpr float ALPHA  = 20.0f;
constexpr float RECW   = 0.7f;
constexpr float THRC   = 0.005f;
constexpr float EPS_BN = 1e-3f;
constexpr int   NIT    = 100;
constexpr int   NVC    = 30;   // split-V chunks for phase-B partials

// ---------------- generic NT GEMM: P[s][m][n] = sum_{k in split s} A[m][k]*B[n][k] ---------
template<bool MULA>
__global__ __launch_bounds__(256)
void gemm_nt(const float* __restrict__ A, const float* __restrict__ A2,
             const float* __restrict__ Bm,
             const float* __restrict__ rsA, const float* __restrict__ rsB,
             float* __restrict__ P, int M, int N, int Kd,
             const int* __restrict__ frozen)
{
  if (frozen && frozen[0]) return;
  const int S = gridDim.z, s = blockIdx.z;
  const int k0 = (int)((long long)Kd * s / S);
  const int k1 = (int)((long long)Kd * (s+1) / S);
  const int m0 = blockIdx.y * 64, n0 = blockIdx.x * 64;
  __shared__ float As[16][68];
  __shared__ float Bs[16][68];
  const int tid = threadIdx.x;
  const int tx = tid & 15, ty = tid >> 4;
  float acc[4][4] = {};
  for (int kc = k0; kc < k1; kc += 16) {
#pragma unroll
    for (int r = 0; r < 4; ++r) {
      int e = tid + 256*r;
      int i = e >> 4, j = e & 15;
      int kk = kc + j;
      int mi = m0 + i, ni = n0 + i;
      float av = 0.f, bv = 0.f;
      if (kk < k1 && mi < M) {
        av = A[(size_t)mi*Kd + kk];
        if (MULA) av *= A2[(size_t)mi*Kd + kk];
        if (rsA) av *= rsA[mi];
      }
      if (kk < k1 && ni < N) {
        bv = Bm[(size_t)ni*Kd + kk];
        if (rsB) bv *= rsB[ni];
      }
      As[j][i] = av;
      Bs[j][i] = bv;
    }
    __syncthreads();
#pragma unroll
    for (int kk = 0; kk < 16; ++kk) {
      float4 a4 = *(const float4*)&As[kk][ty*4];
      float4 b4 = *(const float4*)&Bs[kk][tx*4];
      float a_[4] = {a4.x, a4.y, a4.z, a4.w};
      float b_[4] = {b4.x, b4.y, b4.z, b4.w};
#pragma unroll
      for (int i = 0; i < 4; ++i)
#pragma unroll
        for (int j = 0; j < 4; ++j)
          acc[i][j] += a_[i]*b_[j];
    }
    __syncthreads();
  }
  const size_t base = (size_t)s*M*N;
#pragma unroll
  for (int i = 0; i < 4; ++i) {
    int m = m0 + ty*4 + i;
    if (m >= M) continue;
#pragma unroll
    for (int j = 0; j < 4; ++j) {
      int n = n0 + tx*4 + j;
      if (n < N) P[base + (size_t)m*N + n] = acc[i][j];
    }
  }
}

// ---------------- phase A family: acc[b][v] = sum_k mat[k][v]*uv[k][b] ----------------
// MODE 0: out[b][v] = bm[b][v]/acc           (w or v1)
// MODE 1: err partials red[vb][b] = sum_v |vm*acc - bm|
// MODE 2: out[b][v] = 1 - acc (recon logits), red[vb][b] = rowmax partials
template<int MODE>
__global__ __launch_bounds__(256)
void phaseA(const float* __restrict__ mat, const float* __restrict__ uv,
            const float* __restrict__ bm, const float* __restrict__ vm,
            float* __restrict__ out, float* __restrict__ red,
            const int* __restrict__ frozen)
{
  if (MODE != 2) { if (frozen[0]) return; }
  const int tid = threadIdx.x;
  const int v0 = blockIdx.x*1024 + tid*4;
  const int b0 = blockIdx.y*16;
  __shared__ float us[Kn][16];
  for (int e = tid; e < Kn*16; e += 256)
    us[e >> 4][e & 15] = uv[(size_t)(e >> 4)*Bn + b0 + (e & 15)];
  __syncthreads();
  const bool act = (v0 + 3) < Vn;
  float acc[16][4];
#pragma unroll
  for (int j = 0; j < 16; ++j) { acc[j][0]=0.f; acc[j][1]=0.f; acc[j][2]=0.f; acc[j][3]=0.f; }
  if (act) {
    const float* mp = mat + v0;
    for (int k = 0; k < Kn; ++k) {
      const float4 kv = *(const float4*)mp; mp += Vn;
      float uk[16];
      *(float4*)&uk[0]  = *(const float4*)&us[k][0];
      *(float4*)&uk[4]  = *(const float4*)&us[k][4];
      *(float4*)&uk[8]  = *(const float4*)&us[k][8];
      *(float4*)&uk[12] = *(const float4*)&us[k][12];
#pragma unroll
      for (int j = 0; j < 16; ++j) {
        acc[j][0] += uk[j]*kv.x;
        acc[j][1] += uk[j]*kv.y;
        acc[j][2] += uk[j]*kv.z;
        acc[j][3] += uk[j]*kv.w;
      }
    }
  }
  if constexpr (MODE == 0) {
    if (act) {
#pragma unroll
      for (int j = 0; j < 16; ++j) {
        const size_t o = (size_t)(b0+j)*Vn + v0;
        const float4 bb = *(const float4*)&bm[o];
        float4 w;
        w.x = bb.x/acc[j][0]; w.y = bb.y/acc[j][1];
        w.z = bb.z/acc[j][2]; w.w = bb.w/acc[j][3];
        *(float4*)&out[o] = w;
      }
    }
  } else if constexpr (MODE == 1) {
    __shared__ float rs[16][256];
    float es[16];
#pragma unroll
    for (int j = 0; j < 16; ++j) es[j] = 0.f;
    if (act) {
#pragma unroll
      for (int j = 0; j < 16; ++j) {
        const size_t o = (size_t)(b0+j)*Vn + v0;
        const float4 bb = *(const float4*)&bm[o];
        const float4 vv = *(const float4*)&vm[o];
        es[j] = fabsf(vv.x*acc[j][0] - bb.x) + fabsf(vv.y*acc[j][1] - bb.y)
              + fabsf(vv.z*acc[j][2] - bb.z) + fabsf(vv.w*acc[j][3] - bb.w);
      }
    }
#pragma unroll
    for (int j = 0; j < 16; ++j) rs[j][tid] = es[j];
    __syncthreads();
    for (int st = 128; st; st >>= 1) {
      if (tid < st) {
#pragma unroll
        for (int j = 0; j < 16; ++j) rs[j][tid] += rs[j][tid+st];
      }
      __syncthreads();
    }
    if (tid < 16) red[(size_t)blockIdx.x*Bn + b0 + tid] = rs[tid][0];
  } else {
    __shared__ float rs[16][256];
    float mxv[16];
#pragma unroll
    for (int j = 0; j < 16; ++j) mxv[j] = -1e30f;
    if (act) {
#pragma unroll
      for (int j = 0; j < 16; ++j) {
        const size_t o = (size_t)(b0+j)*Vn + v0;
        float4 rr;
        rr.x = 1.f - acc[j][0]; rr.y = 1.f - acc[j][1];
        rr.z = 1.f - acc[j][2]; rr.w = 1.f - acc[j][3];
        *(float4*)&out[o] = rr;
        mxv[j] = fmaxf(fmaxf(rr.x, rr.y), fmaxf(rr.z, rr.w));
      }
    }
#pragma unroll
    for (int j = 0; j < 16; ++j) rs[j][tid] = mxv[j];
    __syncthreads();
    for (int st = 128; st; st >>= 1) {
      if (tid < st) {
#pragma unroll
        for (int j = 0; j < 16; ++j) rs[j][tid] = fmaxf(rs[j][tid], rs[j][tid+st]);
      }
      __syncthreads();
    }
    if (tid < 16) red[(size_t)blockIdx.x*Bn + b0 + tid] = rs[tid][0];
  }
}

// ---------------- small kernels ----------------
__global__ void rowNorms(const float* __restrict__ X, float* __restrict__ rn, int R, int C)
{
  int wv = threadIdx.x >> 6, lane = threadIdx.x & 63;
  int r = blockIdx.x*4 + wv;
  if (r >= R) return;
  float s = 0.f;
  for (int c = lane; c < C; c += 64) { float x = X[(size_t)r*C + c]; s += x*x; }
#pragma unroll
  for (int m = 32; m; m >>= 1) s += __shfl_xor(s, m, 64);
  if (lane == 0) rn[r] = 1.f / fmaxf(sqrtf(s), 1e-12f);
}

__global__ void epiCostKern(const float* __restrict__ P, float* __restrict__ cost,
                            float* __restrict__ kern)
{
  for (size_t i = (size_t)blockIdx.x*blockDim.x + threadIdx.x; i < (size_t)Kn*Vn;
       i += (size_t)gridDim.x*blockDim.x) {
    float c = 1.f - P[i];
    cost[i] = c;
    kern[i] = expf(-ALPHA * c);
  }
}

__global__ void epiH(const float* __restrict__ P, const float* __restrict__ b1,
                     float* __restrict__ h, int S)
{
  int i = blockIdx.x*blockDim.x + threadIdx.x;
  if (i >= Bn*Hn) return;
  float v = b1[i & (Hn-1)];
  for (int s = 0; s < S; ++s) v += P[(size_t)s*Bn*Hn + i];
  h[i] = fmaxf(v, 0.f);
}

__global__ void bnStats(const float* __restrict__ P, const float* __restrict__ b2,
                        float* __restrict__ mu, float* __restrict__ ivar, int S)
{
  int k = blockIdx.x, b = threadIdx.x;
  float z = b2[k];
  for (int s = 0; s < S; ++s) z += P[((size_t)s*Bn + b)*Kn + k];
  __shared__ float r1[256], r2[256];
  r1[b] = z; r2[b] = z*z; __syncthreads();
  for (int st = 128; st; st >>= 1) {
    if (b < st) { r1[b] += r1[b+st]; r2[b] += r2[b+st]; }
    __syncthreads();
  }
  if (b == 0) {
    float m = r1[0]/Bn, v = r2[0]/Bn - (r1[0]/Bn)*(r1[0]/Bn);
    mu[k] = m; ivar[k] = rsqrtf(v + EPS_BN);
  }
}

__global__ void bnSoftmax(const float* __restrict__ P, const float* __restrict__ b2,
                          const float* __restrict__ mu, const float* __restrict__ ivar,
                          const float* __restrict__ gamma, const float* __restrict__ beta,
                          float* __restrict__ a, int S)
{
  int b = blockIdx.x, k = threadIdx.x;
  float zn = -1e30f;
  if (k < Kn) {
    float z = b2[k];
    for (int s = 0; s < S; ++s) z += P[((size_t)s*Bn + b)*Kn + k];
    zn = gamma[k]*(z - mu[k])*ivar[k] + beta[k];
  }
  __shared__ float red[256];
  red[k] = zn; __syncthreads();
  for (int st = 128; st; st >>= 1) { if (k < st) red[k] = fmaxf(red[k], red[k+st]); __syncthreads(); }
  float mx = red[0]; __syncthreads();
  float e = (k < Kn) ? expf(zn - mx) : 0.f;
  red[k] = e; __syncthreads();
  for (int st = 128; st; st >>= 1) { if (k < st) red[k] += red[k+st]; __syncthreads(); }
  if (k < Kn) a[(size_t)k*Bn + b] = e / red[0];
}

__global__ __launch_bounds__(512)
void rowSoftmax(const float* __restrict__ bows, float* __restrict__ bm)
{
  int b = blockIdx.x, t = threadIdx.x;
  const float4* row  = (const float4*)(bows + (size_t)b*Vn);
  float4* orow = (float4*)(bm + (size_t)b*Vn);
  __shared__ float red[512];
  float mx = -1e30f;
  for (int v4 = t; v4 < Vn/4; v4 += 512) {
    float4 x = row[v4];
    mx = fmaxf(mx, fmaxf(fmaxf(x.x, x.y), fmaxf(x.z, x.w)));
  }
  red[t] = mx; __syncthreads();
  for (int st = 256; st; st >>= 1) { if (t < st) red[t] = fmaxf(red[t], red[t+st]); __syncthreads(); }
  mx = red[0]; __syncthreads();
  float sum = 0.f;
  for (int v4 = t; v4 < Vn/4; v4 += 512) {
    float4 x = row[v4];
    float4 e;
    e.x = expf(x.x - mx); e.y = expf(x.y - mx);
    e.z = expf(x.z - mx); e.w = expf(x.w - mx);
    orow[v4] = e;
    sum += e.x + e.y + e.z + e.w;
  }
  red[t] = sum; __syncthreads();
  for (int st = 256; st; st >>= 1) { if (t < st) red[t] += red[t+st]; __syncthreads(); }
  float inv = 1.f / red[0];
  for (int v4 = t; v4 < Vn/4; v4 += 512) {
    float4 e = orow[v4];
    e.x *= inv; e.y *= inv; e.z *= inv; e.w *= inv;
    orow[v4] = e;
  }
}

__global__ void initU(float* __restrict__ u)
{
  int i = blockIdx.x*256 + threadIdx.x;
  if (i < Kn*Bn) u[i] = 1.f/Kn;
}

// MODE 0: o = a / sum_s tpart ; MODE 1: o = sum_s tpart
template<int MODE>
__global__ void updateU(const float* __restrict__ tpart, const float* __restrict__ a,
                        float* __restrict__ o, int S, const int* __restrict__ frozen)
{
  if (frozen && frozen[0]) return;
  int i = blockIdx.x*blockDim.x + threadIdx.x;
  if (i >= Kn*Bn) return;
  float t = 0.f;
  for (int s = 0; s < S; ++s) t += tpart[(size_t)s*Kn*Bn + i];
  o[i] = (MODE == 0) ? a[i]/t : t;
}

__global__ void errFin(const float* __restrict__ errp, int nc, int* __restrict__ frozen)
{
  if (frozen[0]) return;
  int b = threadIdx.x;
  float s = 0.f;
  for (int c = 0; c < nc; ++c) s += errp[(size_t)c*Bn + b];
  __shared__ float red[256];
  red[b] = s; __syncthreads();
  for (int st = 128; st; st >>= 1) { if (b < st) red[b] = fmaxf(red[b], red[b+st]); __syncthreads(); }
  if (b == 0 && red[0] <= THRC) frozen[0] = 1;
}

__global__ __launch_bounds__(512)
void recPass2(const float* __restrict__ r, const float* __restrict__ rmaxp,
              const float* __restrict__ bows, float* __restrict__ Lb)
{
  int b = blockIdx.x, t = threadIdx.x;
  float m = -1e30f;
  for (int c = 0; c < NVC; ++c) m = fmaxf(m, rmaxp[(size_t)c*Bn + b]);
  const float4* rr = (const float4*)(r + (size_t)b*Vn);
  const float4* br = (const float4*)(bows + (size_t)b*Vn);
  float se = 0.f, dot = 0.f, bs = 0.f;
  for (int v4 = t; v4 < Vn/4; v4 += 512) {
    float4 x = rr[v4];
    float4 w = br[v4];
    se  += expf(x.x-m) + expf(x.y-m) + expf(x.z-m) + expf(x.w-m);
    dot += w.x*x.x + w.y*x.y + w.z*x.z + w.w*x.w;
    bs  += w.x + w.y + w.z + w.w;
  }
  __shared__ float red[512];
  red[t] = se; __syncthreads();
  for (int st = 256; st; st >>= 1) { if (t < st) red[t] += red[t+st]; __syncthreads(); }
  float seT = red[0]; __syncthreads();
  red[t] = dot; __syncthreads();
  for (int st = 256; st; st >>= 1) { if (t < st) red[t] += red[t+st]; __syncthreads(); }
  float dotT = red[0]; __syncthreads();
  red[t] = bs; __syncthreads();
  for (int st = 256; st; st >>= 1) { if (t < st) red[t] += red[t+st]; __syncthreads(); }
  if (t == 0) Lb[b] = dotT - (m + logf(seT))*red[0];
}

__global__ void finalOut(const float* __restrict__ u, const float* __restrict__ t2,
                         const float* __restrict__ Lb, float* __restrict__ outp)
{
  int b = threadIdx.x;
  float sl = 0.f;
  for (int k = 0; k < Kn; ++k) sl += u[(size_t)k*Bn + b]*t2[(size_t)k*Bn + b];
  __shared__ float r1[256], r2[256];
  r1[b] = sl; r2[b] = Lb[b]; __syncthreads();
  for (int st = 128; st; st >>= 1) {
    if (b < st) { r1[b] += r1[b+st]; r2[b] += r2[b+st]; }
    __syncthreads();
  }
  if (b == 0) {
    outp[0] = RECW * (-(r2[0] / (float)Bn));
    outp[1] = r1[0] / (float)Bn;
  }
}

extern "C" void kernel_launch(void* const* d_in, const int* in_sizes, int n_in,
                              void* d_out, int out_size, void* d_ws, size_t ws_size,
                              hipStream_t stream)
{
  const float* bows  = (const float*)d_in[0];
  const float* W1    = (const float*)d_in[1];
  const float* b1    = (const float*)d_in[2];
  const float* W2    = (const float*)d_in[3];
  const float* b2    = (const float*)d_in[4];
  const float* gamma = (const float*)d_in[5];
  const float* beta  = (const float*)d_in[6];
  const float* wemb  = (const float*)d_in[7];
  const float* temb  = (const float*)d_in[8];
  float* out = (float*)d_out;

  float* ws = (float*)d_ws;
  size_t off = 0;
  auto alloc = [&](size_t n) { float* p = ws + off; off += (n + 63) & ~(size_t)63; return p; };
  float* cost  = alloc((size_t)Kn*Vn);
  float* kern  = alloc((size_t)Kn*Vn);
  float* bmat  = alloc((size_t)Bn*Vn);
  float* wbuf  = alloc((size_t)Bn*Vn);   // w temp / GEMM partials / recon logits
  float* vbuf  = alloc((size_t)Bn*Vn);
  float* tpart = alloc((size_t)NVC*Kn*Bn);
  float* hbuf  = alloc((size_t)Bn*Hn);
  float* abuf  = alloc((size_t)Kn*Bn);
  float* ubuf  = alloc((size_t)Kn*Bn);
  float* t2    = alloc((size_t)Kn*Bn);
  float* rnT   = alloc(Kn);
  float* rnW   = alloc(Vn);
  float* mu    = alloc(Kn);
  float* ivar  = alloc(Kn);
  float* errp  = alloc((size_t)NVC*Bn);
  float* rmaxp = alloc((size_t)NVC*Bn);
  float* Lb    = alloc(Bn);
  int* frozen = (int*)(ws + off); off += 64;
  if (off * sizeof(float) > ws_size) return;  // insufficient workspace

  hipMemsetAsync(frozen, 0, sizeof(int), stream);

  // ---- topic_word: cost + kernel ----
  rowNorms<<<CDIV(Kn,4), 256, 0, stream>>>(temb, rnT, Kn, En);
  rowNorms<<<CDIV(Vn,4), 256, 0, stream>>>(wemb, rnW, Vn, En);
  {
    dim3 g(CDIV(Vn,64), CDIV(Kn,64), 1);
    gemm_nt<false><<<g, 256, 0, stream>>>(temb, nullptr, wemb, rnT, rnW, wbuf, Kn, Vn, En, nullptr);
  }
  epiCostKern<<<1024, 256, 0, stream>>>(wbuf, cost, kern);

  // ---- encoder ----
  {
    dim3 g(CDIV(Hn,64), CDIV(Bn,64), 8);
    gemm_nt<false><<<g, 256, 0, stream>>>(bows, nullptr, W1, nullptr, nullptr, wbuf, Bn, Hn, Vn, nullptr);
  }
  epiH<<<CDIV(Bn*Hn,256), 256, 0, stream>>>(wbuf, b1, hbuf, 8);
  {
    dim3 g(CDIV(Kn,64), CDIV(Bn,64), 4);
    gemm_nt<false><<<g, 256, 0, stream>>>(hbuf, nullptr, W2, nullptr, nullptr, wbuf, Bn, Kn, Hn, nullptr);
  }
  bnStats<<<Kn, 256, 0, stream>>>(wbuf, b2, mu, ivar, 4);
  bnSoftmax<<<Bn, 256, 0, stream>>>(wbuf, b2, mu, ivar, gamma, beta, abuf, 4);
  rowSoftmax<<<Bn, 512, 0, stream>>>(bows, bmat);
  initU<<<CDIV(Kn*Bn,256), 256, 0, stream>>>(ubuf);

  // ---- sinkhorn loop ----
  dim3 gA(CDIV(Vn,1024), Bn/16);
  dim3 gB(CDIV(Bn,64), CDIV(Kn,64), NVC);
  for (int it = 0; it < NIT; ++it) {
    phaseA<0><<<gA, 256, 0, stream>>>(kern, ubuf, bmat, nullptr, wbuf, nullptr, frozen);
    gemm_nt<false><<<gB, 256, 0, stream>>>(kern, nullptr, wbuf, nullptr, nullptr, tpart, Kn, Bn, Vn, frozen);
    updateU<0><<<CDIV(Kn*Bn,256), 256, 0, stream>>>(tpart, abuf, ubuf, NVC, frozen);
    if (it % 20 == 0) {
      phaseA<0><<<gA, 256, 0, stream>>>(kern, ubuf, bmat, nullptr, vbuf, nullptr, frozen);
      gemm_nt<false><<<gB, 256, 0, stream>>>(kern, nullptr, vbuf, nullptr, nullptr, tpart, Kn, Bn, Vn, frozen);
      updateU<0><<<CDIV(Kn*Bn,256), 256, 0, stream>>>(tpart, abuf, ubuf, NVC, frozen);
      phaseA<1><<<gA, 256, 0, stream>>>(kern, ubuf, bmat, vbuf, nullptr, errp, frozen);
      errFin<<<1, 256, 0, stream>>>(errp, NVC, frozen);
    }
  }

  // ---- reconstruction loss ----
  phaseA<2><<<gA, 256, 0, stream>>>(cost, abuf, nullptr, nullptr, wbuf, rmaxp, frozen);
  recPass2<<<Bn, 512, 0, stream>>>(wbuf, rmaxp, bows, Lb);

  // ---- sinkhorn loss ----
  gemm_nt<true><<<gB, 256, 0, stream>>>(kern, cost, vbuf, nullptr, nullptr, tpart, Kn, Bn, Vn, nullptr);
  updateU<1><<<CDIV(Kn*Bn,256), 256, 0, stream>>>(tpart, nullptr, t2, NVC, nullptr);
  finalOut<<<1, 256, 0, stream>>>(ubuf, t2, Lb, out);
}

// Round 3
// 3905.725 us; speedup vs baseline: 1.5485x; 1.5485x over previous
//
#include <hip/hip_runtime.h>
#include <math.h>

#define CDIV(a,b) (((a)+(b)-1)/(b))

typedef unsigned short u16;
typedef unsigned long long u64;
typedef __attribute__((ext_vector_type(8))) short bf16x8;
typedef __attribute__((ext_vector_type(4))) float f32x4;

constexpr int Bn = 256;
constexpr int Vn = 30000;
constexpr int Hn = 512;
constexpr int Kn = 200;
constexpr int En = 300;
constexpr int Kp = 224;          // K padded to 7*32 for MFMA
constexpr int Vc = 480;          // v-chunk per block
constexpr int NCH = 63;          // # chunks (63*480 = 30240)
constexpr int Vpad = NCH * Vc;   // 30240
constexpr int NVC_R = 30;        // recon-path split (VALU kernel)
constexpr float ALPHA  = 20.0f;
constexpr float RECW   = 0.7f;
constexpr float THRC   = 0.005f;
constexpr float EPS_BN = 1e-3f;
constexpr int   NIT    = 100;

__device__ __forceinline__ float bf2f(u16 h) {
  union { unsigned u; float f; } c; c.u = (unsigned)h << 16; return c.f;
}
__device__ __forceinline__ u16 f2bf(float f) {
  union { float f; unsigned u; } c; c.f = f;
  return (u16)((c.u + 0x7fffu + ((c.u >> 16) & 1u)) >> 16);
}

// ================= fused sinkhorn iteration (MFMA bf16) =================
// MODE 0: w = bm/(kernT@u) in LDS, then tpart = kern@w partials
// MODE 1: MODE 0 + also store w to global wout (v1 for check iterations)
// MODE 2: err partials only: errp[c][b] = sum_v |win*(kernT@u) - bm|
// MODE 3: final loss: tpart = kernA@win (win read from global, phase A skipped)
template<int MODE>
__global__ __launch_bounds__(256, 2)
void fusedAB(const u16* __restrict__ kernT, const u16* __restrict__ kernA,
             const u16* __restrict__ ub, const u16* __restrict__ bmb,
             u16* __restrict__ wout, const u16* __restrict__ win,
             float* __restrict__ tpart, float* __restrict__ errp,
             const int* __restrict__ frozen)
{
  if (MODE != 3 && frozen[0]) return;
  const int c = blockIdx.x, g = blockIdx.y;
  const int v0 = c * Vc, b0 = g * 64;
  const int tid = threadIdx.x;
  const int wv = tid >> 6, l = tid & 63, l15 = l & 15, lg = l >> 4;
  const int rloc = wv * 16 + l15;     // local b row (0..63) = D col
  const int bcol = b0 + rloc;         // global b
  __shared__ u16 wlds[64 * Vc];
  char* wbase = (char*)wlds;
  const int sw = (rloc & 7) << 4;     // XOR bank swizzle

  if (MODE != 3) {
    // ---- phase A: denom[v][b] = sum_k kernT[v][k] * u[k][b] ----
    bf16x8 uf[7];
    {
      const u16* up = ub + (size_t)bcol * Kp + lg * 8;
#pragma unroll
      for (int ks = 0; ks < 7; ++ks) uf[ks] = *(const bf16x8*)(up + ks * 32);
    }
    float e = 0.f;
    for (int vt = 0; vt < Vc / 16; ++vt) {
      const u16* ktp = kernT + (size_t)(v0 + vt * 16 + l15) * Kp + lg * 8;
      f32x4 acc = {0.f, 0.f, 0.f, 0.f};
#pragma unroll
      for (int ks = 0; ks < 7; ++ks) {
        bf16x8 kf = *(const bf16x8*)(ktp + ks * 32);
        acc = __builtin_amdgcn_mfma_f32_16x16x32_bf16(kf, uf[ks], acc, 0, 0, 0);
      }
      const int vbase = v0 + vt * 16 + lg * 4;       // global v of acc[0]
      const size_t po = (size_t)bcol * Vpad + vbase;
      u64 bq = *(const u64*)(bmb + po);
      if (MODE == 2) {
        u64 wq = *(const u64*)(win + po);
#pragma unroll
        for (int r = 0; r < 4; ++r) {
          float bm = bf2f((u16)(bq >> (16 * r)));
          float wv_ = bf2f((u16)(wq >> (16 * r)));
          e += fabsf(wv_ * acc[r] - bm);
        }
      } else {
        u64 wq = 0;
#pragma unroll
        for (int r = 0; r < 4; ++r) {
          float bm = bf2f((u16)(bq >> (16 * r)));
          float w = (vbase + r < Vn) ? bm / acc[r] : 0.f;
          wq |= (u64)f2bf(w) << (16 * r);
        }
        *(u64*)(wbase + rloc * (Vc * 2) + ((vt * 32 + lg * 8) ^ sw)) = wq;
        if (MODE == 1) *(u64*)(wout + po) = wq;
      }
    }
    if (MODE == 2) {
      e += __shfl_xor(e, 16, 64);
      e += __shfl_xor(e, 32, 64);
      if (l < 16) errp[c * Bn + bcol] = e;
      return;
    }
    __syncthreads();
  }

  // ---- phase B: tpart[c][k][b] = sum_{v in chunk} kernA[k][v] * w[b][v] ----
  f32x4 accB[13];
#pragma unroll
  for (int mt = 0; mt < 13; ++mt) accB[mt] = (f32x4){0.f, 0.f, 0.f, 0.f};
  for (int vs = 0; vs < Vc / 32; ++vs) {
    bf16x8 wf;
    if (MODE == 3) wf = *(const bf16x8*)(win + (size_t)bcol * Vpad + v0 + vs * 32 + lg * 8);
    else wf = *(const bf16x8*)(wbase + rloc * (Vc * 2) + (((vs * 32 + lg * 8) * 2) ^ sw));
    const u16* kap = kernA + (size_t)l15 * Vpad + v0 + vs * 32 + lg * 8;
#pragma unroll
    for (int mt = 0; mt < 13; ++mt) {
      bf16x8 af = *(const bf16x8*)(kap + (size_t)mt * 16 * Vpad);
      accB[mt] = __builtin_amdgcn_mfma_f32_16x16x32_bf16(af, wf, accB[mt], 0, 0, 0);
    }
  }
#pragma unroll
  for (int mt = 0; mt < 13; ++mt) {
#pragma unroll
    for (int r = 0; r < 4; ++r) {
      int k = mt * 16 + lg * 4 + r;
      if (k < Kn) tpart[((size_t)c * Kn + k) * Bn + bcol] = accB[mt][r];
    }
  }
}

// ================= prep kernels =================
__global__ void prepKern(const float* __restrict__ P, float* __restrict__ cost,
                         u16* __restrict__ kern_bf, u16* __restrict__ kc_bf)
{
  int k = blockIdx.y;
  int v = blockIdx.x * 256 + threadIdx.x;
  if (v >= Vpad) return;
  float cf = 0.f, kf = 0.f;
  if (k < Kn && v < Vn) {
    cf = 1.f - P[(size_t)k * Vn + v];
    kf = expf(-ALPHA * cf);
    cost[(size_t)k * Vn + v] = cf;
  }
  size_t o = (size_t)k * Vpad + v;
  kern_bf[o] = f2bf(kf);
  kc_bf[o]   = f2bf(kf * cf);
}

__global__ void transposeK(const u16* __restrict__ kern_bf, u16* __restrict__ kernT)
{
  __shared__ u16 t[32][33];
  int tx = threadIdx.x & 31, ty = threadIdx.x >> 5;  // 32 x 8
  int v0 = blockIdx.x * 32, k0 = blockIdx.y * 32;
#pragma unroll
  for (int r = 0; r < 4; ++r) t[ty + 8 * r][tx] = kern_bf[(size_t)(k0 + ty + 8 * r) * Vpad + v0 + tx];
  __syncthreads();
#pragma unroll
  for (int r = 0; r < 4; ++r) kernT[(size_t)(v0 + ty + 8 * r) * Kp + k0 + tx] = t[tx][ty + 8 * r];
}

// ================= generic NT GEMM (f32 VALU, prologue only) =================
template<bool MULA>
__global__ __launch_bounds__(256)
void gemm_nt(const float* __restrict__ A, const float* __restrict__ A2,
             const float* __restrict__ Bm,
             const float* __restrict__ rsA, const float* __restrict__ rsB,
             float* __restrict__ P, int M, int N, int Kd,
             const int* __restrict__ frozen)
{
  if (frozen && frozen[0]) return;
  const int S = gridDim.z, s = blockIdx.z;
  const int k0 = (int)((long long)Kd * s / S);
  const int k1 = (int)((long long)Kd * (s + 1) / S);
  const int m0 = blockIdx.y * 64, n0 = blockIdx.x * 64;
  __shared__ float As[16][68];
  __shared__ float Bs[16][68];
  const int tid = threadIdx.x;
  const int tx = tid & 15, ty = tid >> 4;
  float acc[4][4] = {};
  for (int kc = k0; kc < k1; kc += 16) {
#pragma unroll
    for (int r = 0; r < 4; ++r) {
      int e = tid + 256 * r;
      int i = e >> 4, j = e & 15;
      int kk = kc + j;
      int mi = m0 + i, ni = n0 + i;
      float av = 0.f, bv = 0.f;
      if (kk < k1 && mi < M) {
        av = A[(size_t)mi * Kd + kk];
        if (MULA) av *= A2[(size_t)mi * Kd + kk];
        if (rsA) av *= rsA[mi];
      }
      if (kk < k1 && ni < N) {
        bv = Bm[(size_t)ni * Kd + kk];
        if (rsB) bv *= rsB[ni];
      }
      As[j][i] = av;
      Bs[j][i] = bv;
    }
    __syncthreads();
#pragma unroll
    for (int kk = 0; kk < 16; ++kk) {
      float4 a4 = *(const float4*)&As[kk][ty * 4];
      float4 b4 = *(const float4*)&Bs[kk][tx * 4];
      float a_[4] = {a4.x, a4.y, a4.z, a4.w};
      float b_[4] = {b4.x, b4.y, b4.z, b4.w};
#pragma unroll
      for (int i = 0; i < 4; ++i)
#pragma unroll
        for (int j = 0; j < 4; ++j)
          acc[i][j] += a_[i] * b_[j];
    }
    __syncthreads();
  }
  const size_t base = (size_t)s * M * N;
#pragma unroll
  for (int i = 0; i < 4; ++i) {
    int m = m0 + ty * 4 + i;
    if (m >= M) continue;
#pragma unroll
    for (int j = 0; j < 4; ++j) {
      int n = n0 + tx * 4 + j;
      if (n < N) P[base + (size_t)m * N + n] = acc[i][j];
    }
  }
}

// ================= recon logits (f32 VALU, runs once) =================
__global__ __launch_bounds__(256)
void reconA(const float* __restrict__ mat, const float* __restrict__ uv,
            float* __restrict__ out, float* __restrict__ red)
{
  const int tid = threadIdx.x;
  const int v0 = blockIdx.x * 1024 + tid * 4;
  const int b0 = blockIdx.y * 16;
  __shared__ float us[Kn][16];
  for (int e = tid; e < Kn * 16; e += 256)
    us[e >> 4][e & 15] = uv[(size_t)(e >> 4) * Bn + b0 + (e & 15)];
  __syncthreads();
  const bool act = (v0 + 3) < Vn;
  float acc[16][4];
#pragma unroll
  for (int j = 0; j < 16; ++j) { acc[j][0] = 0.f; acc[j][1] = 0.f; acc[j][2] = 0.f; acc[j][3] = 0.f; }
  if (act) {
    const float* mp = mat + v0;
    for (int k = 0; k < Kn; ++k) {
      const float4 kv = *(const float4*)mp; mp += Vn;
      float uk[16];
      *(float4*)&uk[0]  = *(const float4*)&us[k][0];
      *(float4*)&uk[4]  = *(const float4*)&us[k][4];
      *(float4*)&uk[8]  = *(const float4*)&us[k][8];
      *(float4*)&uk[12] = *(const float4*)&us[k][12];
#pragma unroll
      for (int j = 0; j < 16; ++j) {
        acc[j][0] += uk[j] * kv.x;
        acc[j][1] += uk[j] * kv.y;
        acc[j][2] += uk[j] * kv.z;
        acc[j][3] += uk[j] * kv.w;
      }
    }
  }
  __shared__ float rs[16][256];
  float mxv[16];
#pragma unroll
  for (int j = 0; j < 16; ++j) mxv[j] = -1e30f;
  if (act) {
#pragma unroll
    for (int j = 0; j < 16; ++j) {
      const size_t o = (size_t)(b0 + j) * Vn + v0;
      float4 rr;
      rr.x = 1.f - acc[j][0]; rr.y = 1.f - acc[j][1];
      rr.z = 1.f - acc[j][2]; rr.w = 1.f - acc[j][3];
      *(float4*)&out[o] = rr;
      mxv[j] = fmaxf(fmaxf(rr.x, rr.y), fmaxf(rr.z, rr.w));
    }
  }
#pragma unroll
  for (int j = 0; j < 16; ++j) rs[j][tid] = mxv[j];
  __syncthreads();
  for (int st = 128; st; st >>= 1) {
    if (tid < st) {
#pragma unroll
      for (int j = 0; j < 16; ++j) rs[j][tid] = fmaxf(rs[j][tid], rs[j][tid + st]);
    }
    __syncthreads();
  }
  if (tid < 16) red[(size_t)blockIdx.x * Bn + b0 + tid] = rs[tid][0];
}

// ================= small kernels =================
__global__ void rowNorms(const float* __restrict__ X, float* __restrict__ rn, int R, int C)
{
  int wv = threadIdx.x >> 6, lane = threadIdx.x & 63;
  int r = blockIdx.x * 4 + wv;
  if (r >= R) return;
  float s = 0.f;
  for (int c = lane; c < C; c += 64) { float x = X[(size_t)r * C + c]; s += x * x; }
#pragma unroll
  for (int m = 32; m; m >>= 1) s += __shfl_xor(s, m, 64);
  if (lane == 0) rn[r] = 1.f / fmaxf(sqrtf(s), 1e-12f);
}

__global__ void epiH(const float* __restrict__ P, const float* __restrict__ b1,
                     float* __restrict__ h, int S)
{
  int i = blockIdx.x * blockDim.x + threadIdx.x;
  if (i >= Bn * Hn) return;
  float v = b1[i & (Hn - 1)];
  for (int s = 0; s < S; ++s) v += P[(size_t)s * Bn * Hn + i];
  h[i] = fmaxf(v, 0.f);
}

__global__ void bnStats(const float* __restrict__ P, const float* __restrict__ b2,
                        float* __restrict__ mu, float* __restrict__ ivar, int S)
{
  int k = blockIdx.x, b = threadIdx.x;
  float z = b2[k];
  for (int s = 0; s < S; ++s) z += P[((size_t)s * Bn + b) * Kn + k];
  __shared__ float r1[256], r2[256];
  r1[b] = z; r2[b] = z * z; __syncthreads();
  for (int st = 128; st; st >>= 1) {
    if (b < st) { r1[b] += r1[b + st]; r2[b] += r2[b + st]; }
    __syncthreads();
  }
  if (b == 0) {
    float m = r1[0] / Bn, v = r2[0] / Bn - (r1[0] / Bn) * (r1[0] / Bn);
    mu[k] = m; ivar[k] = rsqrtf(v + EPS_BN);
  }
}

__global__ void bnSoftmax(const float* __restrict__ P, const float* __restrict__ b2,
                          const float* __restrict__ mu, const float* __restrict__ ivar,
                          const float* __restrict__ gamma, const float* __restrict__ beta,
                          float* __restrict__ a, int S)
{
  int b = blockIdx.x, k = threadIdx.x;
  float zn = -1e30f;
  if (k < Kn) {
    float z = b2[k];
    for (int s = 0; s < S; ++s) z += P[((size_t)s * Bn + b) * Kn + k];
    zn = gamma[k] * (z - mu[k]) * ivar[k] + beta[k];
  }
  __shared__ float red[256];
  red[k] = zn; __syncthreads();
  for (int st = 128; st; st >>= 1) { if (k < st) red[k] = fmaxf(red[k], red[k + st]); __syncthreads(); }
  float mx = red[0]; __syncthreads();
  float e = (k < Kn) ? expf(zn - mx) : 0.f;
  red[k] = e; __syncthreads();
  for (int st = 128; st; st >>= 1) { if (k < st) red[k] += red[k + st]; __syncthreads(); }
  if (k < Kn) a[(size_t)k * Bn + b] = e / red[0];
}

__global__ __launch_bounds__(512)
void rowSoftmax2(const float* __restrict__ bows, u16* __restrict__ bmb)
{
  int b = blockIdx.x, t = threadIdx.x;
  const float4* row = (const float4*)(bows + (size_t)b * Vn);
  __shared__ float red[512];
  float mx = -1e30f;
  for (int v4 = t; v4 < Vn / 4; v4 += 512) {
    float4 x = row[v4];
    mx = fmaxf(mx, fmaxf(fmaxf(x.x, x.y), fmaxf(x.z, x.w)));
  }
  red[t] = mx; __syncthreads();
  for (int st = 256; st; st >>= 1) { if (t < st) red[t] = fmaxf(red[t], red[t + st]); __syncthreads(); }
  mx = red[0]; __syncthreads();
  float sum = 0.f;
  for (int v4 = t; v4 < Vn / 4; v4 += 512) {
    float4 x = row[v4];
    sum += expf(x.x - mx) + expf(x.y - mx) + expf(x.z - mx) + expf(x.w - mx);
  }
  red[t] = sum; __syncthreads();
  for (int st = 256; st; st >>= 1) { if (t < st) red[t] += red[t + st]; __syncthreads(); }
  float inv = 1.f / red[0];
  for (int v4 = t; v4 < Vn / 4; v4 += 512) {
    float4 x = row[v4];
    u64 q = (u64)f2bf(expf(x.x - mx) * inv)
          | ((u64)f2bf(expf(x.y - mx) * inv) << 16)
          | ((u64)f2bf(expf(x.z - mx) * inv) << 32)
          | ((u64)f2bf(expf(x.w - mx) * inv) << 48);
    *(u64*)(bmb + (size_t)b * Vpad + v4 * 4) = q;
  }
  for (int p = t; p < (Vpad - Vn) / 4; p += 512)
    *(u64*)(bmb + (size_t)b * Vpad + Vn + p * 4) = 0;
}

__global__ void initU2(float* __restrict__ u, u16* __restrict__ ub)
{
  int i = blockIdx.x * 256 + threadIdx.x;   // 200 blocks -> 51200
  int k = i >> 8, b = i & 255;
  u[i] = 1.f / Kn;
  ub[(size_t)b * Kp + k] = f2bf(1.f / Kn);
  if (k < Kp - Kn) ub[(size_t)b * Kp + Kn + k] = 0;
}

__global__ void updateU2(const float* __restrict__ tpart, const float* __restrict__ a,
                         float* __restrict__ u, u16* __restrict__ ub,
                         const int* __restrict__ frozen)
{
  if (frozen[0]) return;
  int i = blockIdx.x * 256 + threadIdx.x;
  float t = 0.f;
#pragma unroll 7
  for (int c = 0; c < NCH; ++c) t += tpart[(size_t)c * Kn * Bn + i];
  float uu = a[i] / t;
  u[i] = uu;
  int k = i >> 8, b = i & 255;
  ub[(size_t)b * Kp + k] = f2bf(uu);
  if (k < Kp - Kn) ub[(size_t)b * Kp + Kn + k] = 0;
}

__global__ void sumT(const float* __restrict__ tpart, float* __restrict__ t2)
{
  int i = blockIdx.x * 256 + threadIdx.x;
  float t = 0.f;
#pragma unroll 7
  for (int c = 0; c < NCH; ++c) t += tpart[(size_t)c * Kn * Bn + i];
  t2[i] = t;
}

__global__ void errFin(const float* __restrict__ errp, int nc, int* __restrict__ frozen)
{
  if (frozen[0]) return;
  int b = threadIdx.x;
  float s = 0.f;
  for (int c = 0; c < nc; ++c) s += errp[(size_t)c * Bn + b];
  __shared__ float red[256];
  red[b] = s; __syncthreads();
  for (int st = 128; st; st >>= 1) { if (b < st) red[b] = fmaxf(red[b], red[b + st]); __syncthreads(); }
  if (b == 0 && red[0] <= THRC) frozen[0] = 1;
}

__global__ __launch_bounds__(512)
void recPass2(const float* __restrict__ r, const float* __restrict__ rmaxp,
              const float* __restrict__ bows, float* __restrict__ Lb)
{
  int b = blockIdx.x, t = threadIdx.x;
  float m = -1e30f;
  for (int c = 0; c < NVC_R; ++c) m = fmaxf(m, rmaxp[(size_t)c * Bn + b]);
  const float4* rr = (const float4*)(r + (size_t)b * Vn);
  const float4* br = (const float4*)(bows + (size_t)b * Vn);
  float se = 0.f, dot = 0.f, bs = 0.f;
  for (int v4 = t; v4 < Vn / 4; v4 += 512) {
    float4 x = rr[v4];
    float4 w = br[v4];
    se  += expf(x.x - m) + expf(x.y - m) + expf(x.z - m) + expf(x.w - m);
    dot += w.x * x.x + w.y * x.y + w.z * x.z + w.w * x.w;
    bs  += w.x + w.y + w.z + w.w;
  }
  __shared__ float red[512];
  red[t] = se; __syncthreads();
  for (int st = 256; st; st >>= 1) { if (t < st) red[t] += red[t + st]; __syncthreads(); }
  float seT = red[0]; __syncthreads();
  red[t] = dot; __syncthreads();
  for (int st = 256; st; st >>= 1) { if (t < st) red[t] += red[t + st]; __syncthreads(); }
  float dotT = red[0]; __syncthreads();
  red[t] = bs; __syncthreads();
  for (int st = 256; st; st >>= 1) { if (t < st) red[t] += red[t + st]; __syncthreads(); }
  if (t == 0) Lb[b] = dotT - (m + logf(seT)) * red[0];
}

__global__ void finalOut(const float* __restrict__ u, const float* __restrict__ t2,
                         const float* __restrict__ Lb, float* __restrict__ outp)
{
  int b = threadIdx.x;
  float sl = 0.f;
  for (int k = 0; k < Kn; ++k) sl += u[(size_t)k * Bn + b] * t2[(size_t)k * Bn + b];
  __shared__ float r1[256], r2[256];
  r1[b] = sl; r2[b] = Lb[b]; __syncthreads();
  for (int st = 128; st; st >>= 1) {
    if (b < st) { r1[b] += r1[b + st]; r2[b] += r2[b + st]; }
    __syncthreads();
  }
  if (b == 0) {
    outp[0] = RECW * (-(r2[0] / (float)Bn));
    outp[1] = r1[0] / (float)Bn;
  }
}

extern "C" void kernel_launch(void* const* d_in, const int* in_sizes, int n_in,
                              void* d_out, int out_size, void* d_ws, size_t ws_size,
                              hipStream_t stream)
{
  const float* bows  = (const float*)d_in[0];
  const float* W1    = (const float*)d_in[1];
  const float* b1    = (const float*)d_in[2];
  const float* W2    = (const float*)d_in[3];
  const float* b2    = (const float*)d_in[4];
  const float* gamma = (const float*)d_in[5];
  const float* beta  = (const float*)d_in[6];
  const float* wemb  = (const float*)d_in[7];
  const float* temb  = (const float*)d_in[8];
  float* out = (float*)d_out;

  float* ws = (float*)d_ws;
  size_t off = 0;
  auto alloc = [&](size_t n) { float* p = ws + off; off += (n + 63) & ~(size_t)63; return p; };
  float* cost   = alloc((size_t)Kn * Vn);
  float* wbuf   = alloc((size_t)Bn * Vn);          // gemm temps / recon logits
  u16*   kern_bf = (u16*)alloc(((size_t)Kp * Vpad + 1) / 2);
  u16*   kc_bf   = (u16*)alloc(((size_t)Kp * Vpad + 1) / 2);
  u16*   kernT   = (u16*)alloc(((size_t)Vpad * Kp + 1) / 2);
  u16*   bm_bf   = (u16*)alloc(((size_t)Bn * Vpad + 1) / 2);
  u16*   vb_bf   = (u16*)alloc(((size_t)Bn * Vpad + 1) / 2);
  u16*   ub_bf   = (u16*)alloc(((size_t)Bn * Kp + 1) / 2);
  float* tpart  = alloc((size_t)NCH * Kn * Bn);
  float* hbuf   = alloc((size_t)Bn * Hn);
  float* abuf   = alloc((size_t)Kn * Bn);
  float* ubuf   = alloc((size_t)Kn * Bn);
  float* t2     = alloc((size_t)Kn * Bn);
  float* rnT    = alloc(Kn);
  float* rnW    = alloc(Vn);
  float* mu     = alloc(Kn);
  float* ivar   = alloc(Kn);
  float* errp   = alloc((size_t)NCH * Bn);
  float* rmaxp  = alloc((size_t)NVC_R * Bn);
  float* Lb     = alloc(Bn);
  int* frozen = (int*)(ws + off); off += 64;
  if (off * sizeof(float) > ws_size) return;

  hipMemsetAsync(frozen, 0, sizeof(int), stream);

  // ---- topic_word -> cost / kern_bf / kc_bf / kernT ----
  rowNorms<<<CDIV(Kn, 4), 256, 0, stream>>>(temb, rnT, Kn, En);
  rowNorms<<<CDIV(Vn, 4), 256, 0, stream>>>(wemb, rnW, Vn, En);
  {
    dim3 g(CDIV(Vn, 64), CDIV(Kn, 64), 1);
    gemm_nt<false><<<g, 256, 0, stream>>>(temb, nullptr, wemb, rnT, rnW, wbuf, Kn, Vn, En, nullptr);
  }
  prepKern<<<dim3(CDIV(Vpad, 256), Kp), 256, 0, stream>>>(wbuf, cost, kern_bf, kc_bf);
  transposeK<<<dim3(Vpad / 32, Kp / 32), 256, 0, stream>>>(kern_bf, kernT);

  // ---- encoder ----
  {
    dim3 g(CDIV(Hn, 64), CDIV(Bn, 64), 8);
    gemm_nt<false><<<g, 256, 0, stream>>>(bows, nullptr, W1, nullptr, nullptr, wbuf, Bn, Hn, Vn, nullptr);
  }
  epiH<<<CDIV(Bn * Hn, 256), 256, 0, stream>>>(wbuf, b1, hbuf, 8);
  {
    dim3 g(CDIV(Kn, 64), CDIV(Bn, 64), 4);
    gemm_nt<false><<<g, 256, 0, stream>>>(hbuf, nullptr, W2, nullptr, nullptr, wbuf, Bn, Kn, Hn, nullptr);
  }
  bnStats<<<Kn, 256, 0, stream>>>(wbuf, b2, mu, ivar, 4);
  bnSoftmax<<<Bn, 256, 0, stream>>>(wbuf, b2, mu, ivar, gamma, beta, abuf, 4);
  rowSoftmax2<<<Bn, 512, 0, stream>>>(bows, bm_bf);
  initU2<<<Kn, 256, 0, stream>>>(ubuf, ub_bf);

  // ---- sinkhorn loop (MFMA fused) ----
  dim3 gF(NCH, Bn / 64);
  for (int it = 0; it < NIT; ++it) {
    fusedAB<0><<<gF, 256, 0, stream>>>(kernT, kern_bf, ub_bf, bm_bf, nullptr, nullptr, tpart, nullptr, frozen);
    updateU2<<<Kn, 256, 0, stream>>>(tpart, abuf, ubuf, ub_bf, frozen);
    if (it % 20 == 0) {
      fusedAB<1><<<gF, 256, 0, stream>>>(kernT, kern_bf, ub_bf, bm_bf, vb_bf, nullptr, tpart, nullptr, frozen);
      updateU2<<<Kn, 256, 0, stream>>>(tpart, abuf, ubuf, ub_bf, frozen);
      fusedAB<2><<<gF, 256, 0, stream>>>(kernT, kern_bf, ub_bf, bm_bf, nullptr, vb_bf, tpart, errp, frozen);
      errFin<<<1, 256, 0, stream>>>(errp, NCH, frozen);
    }
  }

  // ---- reconstruction loss (f32 path) ----
  reconA<<<dim3(CDIV(Vn, 1024), Bn / 16), 256, 0, stream>>>(cost, abuf, wbuf, rmaxp);
  recPass2<<<Bn, 512, 0, stream>>>(wbuf, rmaxp, bows, Lb);

  // ---- sinkhorn loss ----
  fusedAB<3><<<gF, 256, 0, stream>>>(kernT, kc_bf, ub_bf, bm_bf, nullptr, vb_bf, tpart, nullptr, frozen);
  sumT<<<Kn, 256, 0, stream>>>(tpart, t2);
  finalOut<<<1, 256, 0, stream>>>(ubuf, t2, Lb, out);
}

// Round 5
// 2255.719 us; speedup vs baseline: 2.6813x; 1.7315x over previous
//
#include <hip/hip_runtime.h>
#include <math.h>

#define CDIV(a,b) (((a)+(b)-1)/(b))

typedef unsigned short u16;
typedef unsigned long long u64;
typedef __attribute__((ext_vector_type(8))) short bf16x8;
typedef __attribute__((ext_vector_type(4))) float f32x4;

constexpr int Bn = 256;
constexpr int Vn = 30000;
constexpr int Hn = 512;
constexpr int Kn = 200;
constexpr int En = 300;
constexpr int Kp = 224;          // K padded to 7*32 for MFMA
constexpr int Vc = 224;          // v-chunk per block (must be mult of 32)
constexpr int NCH = 135;         // 135*224 = 30240
constexpr int Vpad = NCH * Vc;   // 30240
constexpr float ALPHA  = 20.0f;
constexpr float RECW   = 0.7f;
constexpr float THRC   = 0.005f;
constexpr float EPS_BN = 1e-3f;
constexpr int   NIT    = 100;

__device__ __forceinline__ float bf2f(u16 h) {
  union { unsigned u; float f; } c; c.u = (unsigned)h << 16; return c.f;
}
__device__ __forceinline__ u16 f2bf(float f) {
  union { float f; unsigned u; } c; c.f = f;
  return (u16)((c.u + 0x7fffu + ((c.u >> 16) & 1u)) >> 16);
}

// ================= fused sinkhorn iteration (MFMA bf16) =================
// MODE 0: w = bm/(kernT@u) in LDS, then tpart = kern@w partials (bf16)
// MODE 1: MODE 0 + also store w to global wout (v1 for check iterations)
// MODE 2: err partials only: errp[c][b] = sum_v |win*(kernT@u) - bm|
// MODE 3: final loss: tpart = kernA@win (win from global, phase A skipped)
template<int MODE>
__global__ __launch_bounds__(256, 2)
void fusedAB(const u16* __restrict__ kernT, const u16* __restrict__ kernA,
             const u16* __restrict__ ub, const u16* __restrict__ bmb,
             u16* __restrict__ wout, const u16* __restrict__ win,
             u16* __restrict__ tpart, float* __restrict__ errp,
             const int* __restrict__ frozen)
{
  if (MODE != 3 && frozen[0]) return;
  const int c = blockIdx.x, g = blockIdx.y;
  const int v0 = c * Vc, b0 = g * 64;
  const int tid = threadIdx.x;
  const int wv = tid >> 6, l = tid & 63, l15 = l & 15, lg = l >> 4;
  const int rloc = wv * 16 + l15;     // local b row (0..63) = D col
  const int bcol = b0 + rloc;         // global b
  __shared__ u16 wlds[64 * Vc];
  char* wbase = (char*)wlds;
  const int sw = (rloc & 3) << 4;     // XOR bank swizzle (in-range: bits 4-5)

  if (MODE != 3) {
    // ---- phase A: denom[v][b] = sum_k kernT[v][k] * u[k][b] ----
    bf16x8 uf[7];
    {
      const u16* up = ub + (size_t)bcol * Kp + lg * 8;
#pragma unroll
      for (int ks = 0; ks < 7; ++ks) uf[ks] = *(const bf16x8*)(up + ks * 32);
    }
    float e = 0.f;
    for (int vt = 0; vt < Vc / 16; ++vt) {
      const u16* ktp = kernT + (size_t)(v0 + vt * 16 + l15) * Kp + lg * 8;
      f32x4 acc = {0.f, 0.f, 0.f, 0.f};
#pragma unroll
      for (int ks = 0; ks < 7; ++ks) {
        bf16x8 kf = *(const bf16x8*)(ktp + ks * 32);
        acc = __builtin_amdgcn_mfma_f32_16x16x32_bf16(kf, uf[ks], acc, 0, 0, 0);
      }
      const int vbase = v0 + vt * 16 + lg * 4;       // global v of acc[0]
      const size_t po = (size_t)bcol * Vpad + vbase;
      u64 bq = *(const u64*)(bmb + po);
      if (MODE == 2) {
        u64 wq = *(const u64*)(win + po);
#pragma unroll
        for (int r = 0; r < 4; ++r) {
          float bm = bf2f((u16)(bq >> (16 * r)));
          float wv_ = bf2f((u16)(wq >> (16 * r)));
          e += fabsf(wv_ * acc[r] - bm);
        }
      } else {
        u64 wq = 0;
#pragma unroll
        for (int r = 0; r < 4; ++r) {
          float bm = bf2f((u16)(bq >> (16 * r)));
          float w = (vbase + r < Vn) ? bm / acc[r] : 0.f;
          wq |= (u64)f2bf(w) << (16 * r);
        }
        *(u64*)(wbase + rloc * (Vc * 2) + ((vt * 32 + lg * 8) ^ sw)) = wq;
        if (MODE == 1) *(u64*)(wout + po) = wq;
      }
    }
    if (MODE == 2) {
      e += __shfl_xor(e, 16, 64);
      e += __shfl_xor(e, 32, 64);
      if (l < 16) errp[c * Bn + bcol] = e;
      return;
    }
    __syncthreads();
  }

  // ---- phase B: tpart[c][k][b] = sum_{v in chunk} kernA[k][v] * w[b][v] ----
  f32x4 accB[13];
#pragma unroll
  for (int mt = 0; mt < 13; ++mt) accB[mt] = (f32x4){0.f, 0.f, 0.f, 0.f};
  for (int vs = 0; vs < Vc / 32; ++vs) {
    bf16x8 wf;
    if (MODE == 3) wf = *(const bf16x8*)(win + (size_t)bcol * Vpad + v0 + vs * 32 + lg * 8);
    else wf = *(const bf16x8*)(wbase + rloc * (Vc * 2) + (((vs * 32 + lg * 8) * 2) ^ sw));
    const u16* kap = kernA + (size_t)l15 * Vpad + v0 + vs * 32 + lg * 8;
#pragma unroll
    for (int mt = 0; mt < 13; ++mt) {
      bf16x8 af = *(const bf16x8*)(kap + (size_t)mt * 16 * Vpad);
      accB[mt] = __builtin_amdgcn_mfma_f32_16x16x32_bf16(af, wf, accB[mt], 0, 0, 0);
    }
  }
#pragma unroll
  for (int mt = 0; mt < 13; ++mt) {
#pragma unroll
    for (int r = 0; r < 4; ++r) {
      int k = mt * 16 + lg * 4 + r;
      if (k < Kn) tpart[((size_t)c * Kn + k) * Bn + bcol] = f2bf(accB[mt][r]);
    }
  }
}

// ================= recon logits via MFMA: r[b][v] = 1 - sum_k costT[v][k]*dt[k][b] ====
__global__ __launch_bounds__(256, 2)
void reconMF(const u16* __restrict__ costT, const u16* __restrict__ dtb,
             u16* __restrict__ rbuf)
{
  const int c = blockIdx.x, g = blockIdx.y;
  const int v0 = c * Vc, b0 = g * 64;
  const int tid = threadIdx.x;
  const int wv = tid >> 6, l = tid & 63, l15 = l & 15, lg = l >> 4;
  const int bcol = b0 + wv * 16 + l15;
  bf16x8 uf[7];
  {
    const u16* up = dtb + (size_t)bcol * Kp + lg * 8;
#pragma unroll
    for (int ks = 0; ks < 7; ++ks) uf[ks] = *(const bf16x8*)(up + ks * 32);
  }
  for (int vt = 0; vt < Vc / 16; ++vt) {
    const u16* ktp = costT + (size_t)(v0 + vt * 16 + l15) * Kp + lg * 8;
    f32x4 acc = {0.f, 0.f, 0.f, 0.f};
#pragma unroll
    for (int ks = 0; ks < 7; ++ks) {
      bf16x8 kf = *(const bf16x8*)(ktp + ks * 32);
      acc = __builtin_amdgcn_mfma_f32_16x16x32_bf16(kf, uf[ks], acc, 0, 0, 0);
    }
    const int vbase = v0 + vt * 16 + lg * 4;
    u64 q = 0;
#pragma unroll
    for (int r = 0; r < 4; ++r) q |= (u64)f2bf(1.f - acc[r]) << (16 * r);
    *(u64*)(rbuf + (size_t)bcol * Vpad + vbase) = q;
  }
}

// ================= prep kernels =================
__global__ void prepKern(const float* __restrict__ P, u16* __restrict__ kern_bf,
                         u16* __restrict__ kc_bf, u16* __restrict__ cost_bf)
{
  int k = blockIdx.y;
  int v = blockIdx.x * 256 + threadIdx.x;
  if (v >= Vpad) return;
  float cf = 0.f, kf = 0.f;
  if (k < Kn && v < Vn) {
    cf = 1.f - P[(size_t)k * Vn + v];
    kf = expf(-ALPHA * cf);
  }
  size_t o = (size_t)k * Vpad + v;
  kern_bf[o] = f2bf(kf);
  kc_bf[o]   = f2bf(kf * cf);
  cost_bf[o] = f2bf(cf);
}

__global__ void transposeK(const u16* __restrict__ src, u16* __restrict__ dst)
{
  __shared__ u16 t[32][33];
  int tx = threadIdx.x & 31, ty = threadIdx.x >> 5;  // 32 x 8
  int v0 = blockIdx.x * 32, k0 = blockIdx.y * 32;
#pragma unroll
  for (int r = 0; r < 4; ++r) t[ty + 8 * r][tx] = src[(size_t)(k0 + ty + 8 * r) * Vpad + v0 + tx];
  __syncthreads();
#pragma unroll
  for (int r = 0; r < 4; ++r) dst[(size_t)(v0 + ty + 8 * r) * Kp + k0 + tx] = t[tx][ty + 8 * r];
}

// ================= generic NT GEMM (f32 VALU, prologue only) =================
// float4 staging; requires k-slice starts aligned to 4 (all call sites satisfy)
__global__ __launch_bounds__(256)
void gemm_nt(const float* __restrict__ A, const float* __restrict__ Bm,
             const float* __restrict__ rsA, const float* __restrict__ rsB,
             float* __restrict__ P, int M, int N, int Kd)
{
  const int S = gridDim.z, s = blockIdx.z;
  const int k0 = (int)((long long)Kd * s / S);
  const int k1 = (int)((long long)Kd * (s + 1) / S);
  const int m0 = blockIdx.y * 64, n0 = blockIdx.x * 64;
  __shared__ float As[16][68];
  __shared__ float Bs[16][68];
  const int tid = threadIdx.x;
  const int tx = tid & 15, ty = tid >> 4;
  const int lrow = tid >> 2, lkg = (tid & 3) * 4;
  const int mi = m0 + lrow, ni = n0 + lrow;
  float acc[4][4] = {};
  for (int kc = k0; kc < k1; kc += 16) {
    float4 a4 = {0.f, 0.f, 0.f, 0.f}, b4 = {0.f, 0.f, 0.f, 0.f};
    if (kc + 16 <= k1) {
      if (mi < M) a4 = *(const float4*)&A[(size_t)mi * Kd + kc + lkg];
      if (ni < N) b4 = *(const float4*)&Bm[(size_t)ni * Kd + kc + lkg];
    } else {
      float ta[4] = {0.f, 0.f, 0.f, 0.f}, tb[4] = {0.f, 0.f, 0.f, 0.f};
      for (int jj = 0; jj < 4; ++jj) {
        int kk = kc + lkg + jj;
        if (kk < k1) {
          if (mi < M) ta[jj] = A[(size_t)mi * Kd + kk];
          if (ni < N) tb[jj] = Bm[(size_t)ni * Kd + kk];
        }
      }
      a4.x = ta[0]; a4.y = ta[1]; a4.z = ta[2]; a4.w = ta[3];
      b4.x = tb[0]; b4.y = tb[1]; b4.z = tb[2]; b4.w = tb[3];
    }
    if (rsA && mi < M) { float sc = rsA[mi]; a4.x *= sc; a4.y *= sc; a4.z *= sc; a4.w *= sc; }
    if (rsB && ni < N) { float sc = rsB[ni]; b4.x *= sc; b4.y *= sc; b4.z *= sc; b4.w *= sc; }
    As[lkg + 0][lrow] = a4.x; As[lkg + 1][lrow] = a4.y;
    As[lkg + 2][lrow] = a4.z; As[lkg + 3][lrow] = a4.w;
    Bs[lkg + 0][lrow] = b4.x; Bs[lkg + 1][lrow] = b4.y;
    Bs[lkg + 2][lrow] = b4.z; Bs[lkg + 3][lrow] = b4.w;
    __syncthreads();
#pragma unroll
    for (int kk = 0; kk < 16; ++kk) {
      float4 av = *(const float4*)&As[kk][ty * 4];
      float4 bv = *(const float4*)&Bs[kk][tx * 4];
      float a_[4] = {av.x, av.y, av.z, av.w};
      float b_[4] = {bv.x, bv.y, bv.z, bv.w};
#pragma unroll
      for (int i = 0; i < 4; ++i)
#pragma unroll
        for (int j = 0; j < 4; ++j)
          acc[i][j] += a_[i] * b_[j];
    }
    __syncthreads();
  }
  const size_t base = (size_t)s * M * N;
#pragma unroll
  for (int i = 0; i < 4; ++i) {
    int m = m0 + ty * 4 + i;
    if (m >= M) continue;
#pragma unroll
    for (int j = 0; j < 4; ++j) {
      int n = n0 + tx * 4 + j;
      if (n < N) P[base + (size_t)m * N + n] = acc[i][j];
    }
  }
}

// ================= small kernels =================
__global__ void rowNorms(const float* __restrict__ X, float* __restrict__ rn, int R, int C)
{
  int wv = threadIdx.x >> 6, lane = threadIdx.x & 63;
  int r = blockIdx.x * 4 + wv;
  if (r >= R) return;
  float s = 0.f;
  for (int c = lane; c < C; c += 64) { float x = X[(size_t)r * C + c]; s += x * x; }
#pragma unroll
  for (int m = 32; m; m >>= 1) s += __shfl_xor(s, m, 64);
  if (lane == 0) rn[r] = 1.f / fmaxf(sqrtf(s), 1e-12f);
}

__global__ void epiH(const float* __restrict__ P, const float* __restrict__ b1,
                     float* __restrict__ h, int S)
{
  int i = blockIdx.x * blockDim.x + threadIdx.x;
  if (i >= Bn * Hn) return;
  float v = b1[i & (Hn - 1)];
  for (int s = 0; s < S; ++s) v += P[(size_t)s * Bn * Hn + i];
  h[i] = fmaxf(v, 0.f);
}

__global__ void bnStats(const float* __restrict__ P, const float* __restrict__ b2,
                        float* __restrict__ mu, float* __restrict__ ivar, int S)
{
  int k = blockIdx.x, b = threadIdx.x;
  float z = b2[k];
  for (int s = 0; s < S; ++s) z += P[((size_t)s * Bn + b) * Kn + k];
  __shared__ float r1[256], r2[256];
  r1[b] = z; r2[b] = z * z; __syncthreads();
  for (int st = 128; st; st >>= 1) {
    if (b < st) { r1[b] += r1[b + st]; r2[b] += r2[b + st]; }
    __syncthreads();
  }
  if (b == 0) {
    float m = r1[0] / Bn, v = r2[0] / Bn - (r1[0] / Bn) * (r1[0] / Bn);
    mu[k] = m; ivar[k] = rsqrtf(v + EPS_BN);
  }
}

__global__ void bnSoftmax(const float* __restrict__ P, const float* __restrict__ b2,
                          const float* __restrict__ mu, const float* __restrict__ ivar,
                          const float* __restrict__ gamma, const float* __restrict__ beta,
                          float* __restrict__ a, u16* __restrict__ dtb, int S)
{
  int b = blockIdx.x, k = threadIdx.x;
  float zn = -1e30f;
  if (k < Kn) {
    float z = b2[k];
    for (int s = 0; s < S; ++s) z += P[((size_t)s * Bn + b) * Kn + k];
    zn = gamma[k] * (z - mu[k]) * ivar[k] + beta[k];
  }
  __shared__ float red[256];
  red[k] = zn; __syncthreads();
  for (int st = 128; st; st >>= 1) { if (k < st) red[k] = fmaxf(red[k], red[k + st]); __syncthreads(); }
  float mx = red[0]; __syncthreads();
  float e = (k < Kn) ? expf(zn - mx) : 0.f;
  red[k] = e; __syncthreads();
  for (int st = 128; st; st >>= 1) { if (k < st) red[k] += red[k + st]; __syncthreads(); }
  float dt = e / red[0];
  if (k < Kn) a[(size_t)k * Bn + b] = dt;
  if (k < Kp) dtb[(size_t)b * Kp + k] = (k < Kn) ? f2bf(dt) : (u16)0;
}

__global__ __launch_bounds__(512)
void rowSoftmax2(const float* __restrict__ bows, u16* __restrict__ bmb)
{
  int b = blockIdx.x, t = threadIdx.x;
  const float4* row = (const float4*)(bows + (size_t)b * Vn);
  __shared__ float red[512];
  float mx = -1e30f;
  for (int v4 = t; v4 < Vn / 4; v4 += 512) {
    float4 x = row[v4];
    mx = fmaxf(mx, fmaxf(fmaxf(x.x, x.y), fmaxf(x.z, x.w)));
  }
  red[t] = mx; __syncthreads();
  for (int st = 256; st; st >>= 1) { if (t < st) red[t] = fmaxf(red[t], red[t + st]); __syncthreads(); }
  mx = red[0]; __syncthreads();
  float sum = 0.f;
  for (int v4 = t; v4 < Vn / 4; v4 += 512) {
    float4 x = row[v4];
    sum += expf(x.x - mx) + expf(x.y - mx) + expf(x.z - mx) + expf(x.w - mx);
  }
  red[t] = sum; __syncthreads();
  for (int st = 256; st; st >>= 1) { if (t < st) red[t] += red[t + st]; __syncthreads(); }
  float inv = 1.f / red[0];
  for (int v4 = t; v4 < Vn / 4; v4 += 512) {
    float4 x = row[v4];
    u64 q = (u64)f2bf(expf(x.x - mx) * inv)
          | ((u64)f2bf(expf(x.y - mx) * inv) << 16)
          | ((u64)f2bf(expf(x.z - mx) * inv) << 32)
          | ((u64)f2bf(expf(x.w - mx) * inv) << 48);
    *(u64*)(bmb + (size_t)b * Vpad + v4 * 4) = q;
  }
  for (int p = t; p < (Vpad - Vn) / 4; p += 512)
    *(u64*)(bmb + (size_t)b * Vpad + Vn + p * 4) = 0;
}

__global__ void initU2(float* __restrict__ u, u16* __restrict__ ub)
{
  int i = blockIdx.x * 256 + threadIdx.x;   // 200 blocks -> 51200
  int k = i >> 8, b = i & 255;
  u[i] = 1.f / Kn;
  ub[(size_t)b * Kp + k] = f2bf(1.f / Kn);
  if (k < Kp - Kn) ub[(size_t)b * Kp + Kn + k] = 0;
}

__global__ void updateU2(const u16* __restrict__ tpart, const float* __restrict__ a,
                         float* __restrict__ u, u16* __restrict__ ub,
                         const int* __restrict__ frozen)
{
  if (frozen[0]) return;
  int i = blockIdx.x * 256 + threadIdx.x;
  float t = 0.f;
  for (int c = 0; c < NCH; ++c) t += bf2f(tpart[(size_t)c * Kn * Bn + i]);
  float uu = a[i] / t;
  u[i] = uu;
  int k = i >> 8, b = i & 255;
  ub[(size_t)b * Kp + k] = f2bf(uu);
  if (k < Kp - Kn) ub[(size_t)b * Kp + Kn + k] = 0;
}

__global__ void sumT(const u16* __restrict__ tpart, float* __restrict__ t2)
{
  int i = blockIdx.x * 256 + threadIdx.x;
  float t = 0.f;
  for (int c = 0; c < NCH; ++c) t += bf2f(tpart[(size_t)c * Kn * Bn + i]);
  t2[i] = t;
}

__global__ void errFin(const float* __restrict__ errp, int nc, int* __restrict__ frozen)
{
  if (frozen[0]) return;
  int b = threadIdx.x;
  float s = 0.f;
  for (int c = 0; c < nc; ++c) s += errp[(size_t)c * Bn + b];
  __shared__ float red[256];
  red[b] = s; __syncthreads();
  for (int st = 128; st; st >>= 1) { if (b < st) red[b] = fmaxf(red[b], red[b + st]); __syncthreads(); }
  if (b == 0 && red[0] <= THRC) frozen[0] = 1;
}

__global__ __launch_bounds__(512)
void recPass2(const u16* __restrict__ r, const float* __restrict__ bows,
              float* __restrict__ Lb)
{
  int b = blockIdx.x, t = threadIdx.x;
  const float m = 1.0f;   // logits r = 1 - dot(dt,cost) <= 1 always
  const float4* br = (const float4*)(bows + (size_t)b * Vn);
  float se = 0.f, dot = 0.f, bs = 0.f;
  for (int v4 = t; v4 < Vn / 4; v4 += 512) {
    u64 q = *(const u64*)(r + (size_t)b * Vpad + v4 * 4);
    float4 w = br[v4];
    float x0 = bf2f((u16)q), x1 = bf2f((u16)(q >> 16));
    float x2 = bf2f((u16)(q >> 32)), x3 = bf2f((u16)(q >> 48));
    se  += expf(x0 - m) + expf(x1 - m) + expf(x2 - m) + expf(x3 - m);
    dot += w.x * x0 + w.y * x1 + w.z * x2 + w.w * x3;
    bs  += w.x + w.y + w.z + w.w;
  }
  __shared__ float red[512];
  red[t] = se; __syncthreads();
  for (int st = 256; st; st >>= 1) { if (t < st) red[t] += red[t + st]; __syncthreads(); }
  float seT = red[0]; __syncthreads();
  red[t] = dot; __syncthreads();
  for (int st = 256; st; st >>= 1) { if (t < st) red[t] += red[t + st]; __syncthreads(); }
  float dotT = red[0]; __syncthreads();
  red[t] = bs; __syncthreads();
  for (int st = 256; st; st >>= 1) { if (t < st) red[t] += red[t + st]; __syncthreads(); }
  if (t == 0) Lb[b] = dotT - (m + logf(seT)) * red[0];
}

__global__ void finalOut(const float* __restrict__ u, const float* __restrict__ t2,
                         const float* __restrict__ Lb, float* __restrict__ outp)
{
  int b = threadIdx.x;
  float sl = 0.f;
  for (int k = 0; k < Kn; ++k) sl += u[(size_t)k * Bn + b] * t2[(size_t)k * Bn + b];
  __shared__ float r1[256], r2[256];
  r1[b] = sl; r2[b] = Lb[b]; __syncthreads();
  for (int st = 128; st; st >>= 1) {
    if (b < st) { r1[b] += r1[b + st]; r2[b] += r2[b + st]; }
    __syncthreads();
  }
  if (b == 0) {
    outp[0] = RECW * (-(r2[0] / (float)Bn));
    outp[1] = r1[0] / (float)Bn;
  }
}

extern "C" void kernel_launch(void* const* d_in, const int* in_sizes, int n_in,
                              void* d_out, int out_size, void* d_ws, size_t ws_size,
                              hipStream_t stream)
{
  const float* bows  = (const float*)d_in[0];
  const float* W1    = (const float*)d_in[1];
  const float* b1    = (const float*)d_in[2];
  const float* W2    = (const float*)d_in[3];
  const float* b2    = (const float*)d_in[4];
  const float* gamma = (const float*)d_in[5];
  const float* beta  = (const float*)d_in[6];
  const float* wemb  = (const float*)d_in[7];
  const float* temb  = (const float*)d_in[8];
  float* out = (float*)d_out;

  float* ws = (float*)d_ws;
  size_t off = 0;
  auto alloc = [&](size_t n) { float* p = ws + off; off += (n + 63) & ~(size_t)63; return p; };
  float* wbuf    = alloc((size_t)Kn * Vn);                     // gemm temps
  u16*   kern_bf = (u16*)alloc(((size_t)Kp * Vpad + 1) / 2);
  u16*   kc_bf   = (u16*)alloc(((size_t)Kp * Vpad + 1) / 2);
  u16*   cost_bf = (u16*)alloc(((size_t)Kp * Vpad + 1) / 2);
  u16*   kernT   = (u16*)alloc(((size_t)Vpad * Kp + 1) / 2);
  u16*   costT   = (u16*)alloc(((size_t)Vpad * Kp + 1) / 2);
  u16*   bm_bf   = (u16*)alloc(((size_t)Bn * Vpad + 1) / 2);
  u16*   vb_bf   = (u16*)alloc(((size_t)Bn * Vpad + 1) / 2);
  u16*   rbuf    = (u16*)alloc(((size_t)Bn * Vpad + 1) / 2);
  u16*   ub_bf   = (u16*)alloc(((size_t)Bn * Kp + 1) / 2);
  u16*   dt_bf   = (u16*)alloc(((size_t)Bn * Kp + 1) / 2);
  u16*   tpart   = (u16*)alloc(((size_t)NCH * Kn * Bn + 1) / 2);
  float* hbuf    = alloc((size_t)Bn * Hn);
  float* abuf    = alloc((size_t)Kn * Bn);
  float* ubuf    = alloc((size_t)Kn * Bn);
  float* t2      = alloc((size_t)Kn * Bn);
  float* rnT     = alloc(Kn);
  float* rnW     = alloc(Vn);
  float* mu      = alloc(Kn);
  float* ivar    = alloc(Kn);
  float* errp    = alloc((size_t)NCH * Bn);
  float* Lb      = alloc(Bn);
  int* frozen = (int*)(ws + off); off += 64;
  if (off * sizeof(float) > ws_size) return;

  hipMemsetAsync(frozen, 0, sizeof(int), stream);

  // ---- topic_word -> kern/kc/cost (bf16) + transposes ----
  rowNorms<<<CDIV(Kn, 4), 256, 0, stream>>>(temb, rnT, Kn, En);
  rowNorms<<<CDIV(Vn, 4), 256, 0, stream>>>(wemb, rnW, Vn, En);
  {
    dim3 g(CDIV(Vn, 64), CDIV(Kn, 64), 1);
    gemm_nt<<<g, 256, 0, stream>>>(temb, wemb, rnT, rnW, wbuf, Kn, Vn, En);
  }
  prepKern<<<dim3(CDIV(Vpad, 256), Kp), 256, 0, stream>>>(wbuf, kern_bf, kc_bf, cost_bf);
  transposeK<<<dim3(Vpad / 32, Kp / 32), 256, 0, stream>>>(kern_bf, kernT);
  transposeK<<<dim3(Vpad / 32, Kp / 32), 256, 0, stream>>>(cost_bf, costT);

  // ---- encoder ----
  {
    dim3 g(CDIV(Hn, 64), CDIV(Bn, 64), 25);
    gemm_nt<<<g, 256, 0, stream>>>(bows, W1, nullptr, nullptr, wbuf, Bn, Hn, Vn);
  }
  epiH<<<CDIV(Bn * Hn, 256), 256, 0, stream>>>(wbuf, b1, hbuf, 25);
  {
    dim3 g(CDIV(Kn, 64), CDIV(Bn, 64), 4);
    gemm_nt<<<g, 256, 0, stream>>>(hbuf, W2, nullptr, nullptr, wbuf, Bn, Kn, Hn);
  }
  bnStats<<<Kn, 256, 0, stream>>>(wbuf, b2, mu, ivar, 4);
  bnSoftmax<<<Bn, 256, 0, stream>>>(wbuf, b2, mu, ivar, gamma, beta, abuf, dt_bf, 4);
  rowSoftmax2<<<Bn, 512, 0, stream>>>(bows, bm_bf);
  initU2<<<Kn, 256, 0, stream>>>(ubuf, ub_bf);

  // ---- sinkhorn loop (MFMA fused) ----
  dim3 gF(NCH, Bn / 64);
  for (int it = 0; it < NIT; ++it) {
    fusedAB<0><<<gF, 256, 0, stream>>>(kernT, kern_bf, ub_bf, bm_bf, nullptr, nullptr, tpart, nullptr, frozen);
    updateU2<<<Kn, 256, 0, stream>>>(tpart, abuf, ubuf, ub_bf, frozen);
    if (it % 20 == 0) {
      fusedAB<1><<<gF, 256, 0, stream>>>(kernT, kern_bf, ub_bf, bm_bf, vb_bf, nullptr, tpart, nullptr, frozen);
      updateU2<<<Kn, 256, 0, stream>>>(tpart, abuf, ubuf, ub_bf, frozen);
      fusedAB<2><<<gF, 256, 0, stream>>>(kernT, kern_bf, ub_bf, bm_bf, nullptr, vb_bf, tpart, errp, frozen);
      errFin<<<1, 256, 0, stream>>>(errp, NCH, frozen);
    }
  }

  // ---- reconstruction loss (MFMA path) ----
  reconMF<<<gF, 256, 0, stream>>>(costT, dt_bf, rbuf);
  recPass2<<<Bn, 512, 0, stream>>>(rbuf, bows, Lb);

  // ---- sinkhorn loss ----
  fusedAB<3><<<gF, 256, 0, stream>>>(kernT, kc_bf, ub_bf, bm_bf, nullptr, vb_bf, tpart, nullptr, frozen);
  sumT<<<Kn, 256, 0, stream>>>(tpart, t2);
  finalOut<<<1, 256, 0, stream>>>(ubuf, t2, Lb, out);
}